// Round 4
// baseline (264.682 us; speedup 1.0000x reference)
//
#include <hip/hip_runtime.h>
#include <hip/hip_bf16.h>

#define NS 8192
#define NQ 8192
#define NTOT 16384
#define KDIM 1024
#define ED 512
#define NC 64
#define PBLK 64   // proto partial row-chunks along support dim

typedef __attribute__((ext_vector_type(4))) float fx4;
typedef __attribute__((ext_vector_type(4))) int ix4;
typedef __attribute__((ext_vector_type(8))) short sx8;
typedef __attribute__((ext_vector_type(4))) unsigned short ux4;
typedef __attribute__((ext_vector_type(8))) unsigned short ux8;

__device__ __forceinline__ unsigned short f2bf(float f) {
  union { float f; unsigned u; } v; v.f = f;
  unsigned r = v.u + 0x7fffu + ((v.u >> 16) & 1u);   // RNE
  return (unsigned short)(r >> 16);
}
__device__ __forceinline__ float bf2f(unsigned short h) {
  union { unsigned u; float f; } v; v.u = ((unsigned)h) << 16;
  return v.f;
}

// async global->LDS DMA, 16 B per lane. LDS dest = wave-uniform base + lane*16.
__device__ __forceinline__ void async_ld16(const void* g, void* l) {
  __builtin_amdgcn_global_load_lds(
      (const __attribute__((address_space(1))) unsigned int*)g,
      (__attribute__((address_space(3))) unsigned int*)l, 16, 0, 0);
}

// ---------------------------------------------------------------------------
// K0: W -> Wt bf16 (B^T), 512 blocks; also zeroes rowssq (32 floats/block).
// ---------------------------------------------------------------------------
__global__ __launch_bounds__(256) void k_prep(
    const float* __restrict__ W, unsigned short* __restrict__ Wt,
    float* __restrict__ rowssq) {
  __shared__ float tile[32][33];
  int bid = blockIdx.x;            // 0..511
  int t = threadIdx.x;
  int k0 = (bid & 31) * 32;
  int n0 = (bid >> 5) * 32;
  int tx = t & 31, ty = t >> 5;
#pragma unroll
  for (int i = ty; i < 32; i += 8)
    tile[i][tx] = W[(size_t)(k0 + i) * ED + n0 + tx];
  __syncthreads();
#pragma unroll
  for (int i = ty; i < 32; i += 8)
    Wt[(size_t)(n0 + i) * KDIM + k0 + tx] = f2bf(tile[tx][i]);
  if (t < 32) rowssq[bid * 32 + t] = 0.f;
}

// ---------------------------------------------------------------------------
// K1: emb = bf16(X) @ W + per-row ssq partials, X read as fp32, fused cvt.
// T3/T4 restructure: raw s_barrier + counted vmcnt so the A-path fp32
// prefetch loads SURVIVE the barrier (R1's __syncthreads drained vmcnt(0)
// every iter -> 16 serial HBM latencies -> MfmaUtil 10%).
//   depth-2 A prefetch: loadA(kt+2) issued at iter kt, consumed (cvt +
//   swizzled ds_write) at iter kt+1 after the MFMA block -> a full
//   iteration (~1.3k cyc) covers the ~600-900 cyc X latency.
//   per-iter VMEM FIFO (order pinned by sched_barrier(0)):
//     [8 A(kt+1) from last iter] [4 B(kt+1)] [8 A(kt+2)]
//   writeA's reg deps auto-wait vmcnt<=12 (retires A(kt+1)); explicit
//   s_waitcnt vmcnt(8) retires the 4 B-DMAs; the 8 A(kt+2) loads stay in
//   flight across s_barrier. lgkmcnt(0) commits ds_writes.
//   Tail is uniform-clamped (indices min'd to 15): constant wait counts,
//   redundant-but-harmless re-loads of tile 15.
// LDS layout/swizzle identical to verified round-1 (slot = kq^(m&7)).
// ---------------------------------------------------------------------------
__global__ __launch_bounds__(256) void k_gemm_embed(
    const float* __restrict__ Xs, const float* __restrict__ Xq,
    const unsigned short* __restrict__ Wt,
    unsigned short* __restrict__ emb, float* __restrict__ rowssq) {
  __shared__ unsigned short Ash[2][128 * 8 * 8];  // 16 KB per buf, [m*8+slot][8]
  __shared__ unsigned short Bsh[2][128 * 8 * 8];  // 16 KB per buf, [n*8+slot][8]

  int lid = blockIdx.x;            // 0..511
  int x = lid & 7;                 // xcd (dispatch round-robin heuristic)
  int s = lid >> 3;                // 0..63
  int m_blk = x * 16 + (s >> 2);   // 0..127
  int n_blk = s & 3;               // 0..3

  const float* Xsrc = (m_blk < 64)
      ? (Xs + (size_t)m_blk * 128 * KDIM)
      : (Xq + (size_t)(m_blk - 64) * 128 * KDIM);
  const unsigned short* Wrow = Wt + (size_t)n_blk * 128 * KDIM;

  int t = threadIdx.x;
  int lane = t & 63, w = t >> 6;
  int wm = w >> 1, wn = w & 1;
  int quad = lane >> 4, ml = lane & 15;

  fx4 acc[4][4];
#pragma unroll
  for (int i = 0; i < 4; ++i)
#pragma unroll
    for (int j = 0; j < 4; ++j) acc[i][j] = fx4{0.f, 0.f, 0.f, 0.f};

  fx4 av[2][4][2];   // double-buffered staged A fp32 (2 slots x 4 chunks x 8f)

  auto loadA = [&](int kt, int slot) {
    int k0 = kt * 64;
#pragma unroll
    for (int c = 0; c < 4; ++c) {            // A: 1024 chunks of 8, 4/thread
      int ch = t + 256 * c;
      int m = ch >> 3, kq = ch & 7;          // kq = GLOBAL k-octet
      const float* g = &Xsrc[(size_t)m * KDIM + k0 + kq * 8];
      av[slot][c][0] = *(const fx4*)g;
      av[slot][c][1] = *(const fx4*)(g + 4);
    }
  };
  auto writeA = [&](int slot, int b) {
#pragma unroll
    for (int c = 0; c < 4; ++c) {
      int ch = t + 256 * c;
      int m = ch >> 3, kq = ch & 7;
      ux8 o;
      o[0] = f2bf(av[slot][c][0].x); o[1] = f2bf(av[slot][c][0].y);
      o[2] = f2bf(av[slot][c][0].z); o[3] = f2bf(av[slot][c][0].w);
      o[4] = f2bf(av[slot][c][1].x); o[5] = f2bf(av[slot][c][1].y);
      o[6] = f2bf(av[slot][c][1].z); o[7] = f2bf(av[slot][c][1].w);
      // global kq lands in slot kq^(m&7): identical layout to DMA path
      *(ux8*)&Ash[b][((m * 8) + (kq ^ (m & 7))) * 8] = o;
    }
  };
  auto stageB = [&](int kt, int b) {
    int k0 = kt * 64;
#pragma unroll
    for (int c = 0; c < 4; ++c) {            // B: 1024 chunks, 4/thread
      int ch = t + 256 * c;
      int n = ch >> 3;
      int kq = (ch & 7) ^ (n & 7);           // global-side swizzle
      async_ld16(&Wrow[(size_t)n * KDIM + k0 + kq * 8],
                 &Bsh[b][(w * 64 + 256 * c) * 8]);
    }
  };

  // ---- prologue: FIFO = [4 B(0)] [8 A(0)] [8 A(1)]
  stageB(0, 0);
  __builtin_amdgcn_sched_barrier(0);
  loadA(0, 0);
  loadA(1, 1);
  __builtin_amdgcn_sched_barrier(0);
  writeA(0, 0);        // compiler auto-wait retires B(0)+A(0); A(1) in flight
  asm volatile("s_waitcnt vmcnt(8) lgkmcnt(0)" ::: "memory");
  __builtin_amdgcn_sched_barrier(0);
  __builtin_amdgcn_s_barrier();

  for (int kt = 0; kt < 16; ++kt) {
    int b = kt & 1;
    // entry: buf b staged; av[(kt+1)&1] holds A(kt+1) loads (in flight)
    stageB(kt + 1 < 16 ? kt + 1 : 15, b ^ 1);   // 4 DMAs (oldest this iter)
    __builtin_amdgcn_sched_barrier(0);          // pin FIFO: B before A
    loadA(kt + 2 < 16 ? kt + 2 : 15, b);        // 8 loads -> slot kt&1

    __builtin_amdgcn_s_setprio(1);
#pragma unroll
    for (int s2 = 0; s2 < 2; ++s2) {
      int kq = s2 * 4 + quad;
      sx8 af[4], bfr[4];
#pragma unroll
      for (int i = 0; i < 4; ++i) {
        int row = wm * 64 + i * 16 + ml;
        af[i] = *(const sx8*)&Ash[b][(row * 8 + (kq ^ (row & 7))) * 8];
      }
#pragma unroll
      for (int j = 0; j < 4; ++j) {
        int nrow = wn * 64 + j * 16 + ml;
        bfr[j] = *(const sx8*)&Bsh[b][(nrow * 8 + (kq ^ (nrow & 7))) * 8];
      }
#pragma unroll
      for (int i = 0; i < 4; ++i)
#pragma unroll
        for (int j = 0; j < 4; ++j)
          acc[i][j] = __builtin_amdgcn_mfma_f32_16x16x32_bf16(af[i], bfr[j], acc[i][j], 0, 0, 0);
    }
    __builtin_amdgcn_s_setprio(0);

    writeA(b ^ 1, b ^ 1);   // cvt av[(kt+1)&1] (auto vmcnt wait) -> ds_write
    // retire the 4 B(kt+1) DMAs + commit ds_writes; keep 8 A(kt+2) in flight
    asm volatile("s_waitcnt vmcnt(8) lgkmcnt(0)" ::: "memory");
    __builtin_amdgcn_sched_barrier(0);
    __builtin_amdgcn_s_barrier();
  }

  // epilogue: emb store + row-ssq partial (shfl width-16 + 1 atomic per row)
  int grow = m_blk * 128 + wm * 64;
  int gcol = n_blk * 128 + wn * 64;
#pragma unroll
  for (int i = 0; i < 4; ++i) {
#pragma unroll
    for (int r = 0; r < 4; ++r) {
      int mrow = grow + i * 16 + quad * 4 + r;
      float p = 0.f;
#pragma unroll
      for (int j = 0; j < 4; ++j) {
        emb[(size_t)mrow * ED + gcol + j * 16 + ml] = f2bf(acc[i][j][r]);
        p += acc[i][j][r] * acc[i][j][r];
      }
#pragma unroll
      for (int off = 1; off < 16; off <<= 1) p += __shfl_xor(p, off, 16);
      if (ml == 0) atomicAdd(&rowssq[mrow], p);
    }
  }
}

// ---------------------------------------------------------------------------
// K2: per-class partial sums of (emb_s / ||s||), LDS-accumulated.
// ---------------------------------------------------------------------------
__global__ __launch_bounds__(256) void k_proto_partial(
    const unsigned short* __restrict__ embS, const float* __restrict__ rowssq,
    const int* __restrict__ labels, float* __restrict__ Ppart) {
  __shared__ float Pl[NC * 64];  // 16 KB: [class][dim-within-slice]
  int t = threadIdx.x;
#pragma unroll
  for (int i = 0; i < 16; ++i) Pl[i * 256 + t] = 0.f;
  __syncthreads();

  int w = t >> 6, lane = t & 63;
  int ds = blockIdx.y;            // dim slice: dims [ds*64, ds*64+64)
  int row0 = blockIdx.x * (NS / PBLK);
#pragma unroll 4
  for (int r = w; r < NS / PBLK; r += 4) {
    int row = row0 + r;
    int lbl = labels[row];
    float scale = 1.0f / fmaxf(sqrtf(rowssq[row]), 1e-12f);
    float v = bf2f(embS[(size_t)row * ED + ds * 64 + lane]) * scale;
    atomicAdd(&Pl[lbl * 64 + lane], v);
  }
  __syncthreads();

  float* o = Ppart + (size_t)blockIdx.x * NC * ED + ds * 64;
#pragma unroll
  for (int i = 0; i < 16; ++i) {
    int idx = i * 256 + t;
    o[(size_t)(idx >> 6) * ED + (idx & 63)] = Pl[idx];
  }
}

// ---------------------------------------------------------------------------
// K3: reduce PBLK partials -> Pbf (bf16, MFMA B-fragment layout [kq][n][8]).
// ---------------------------------------------------------------------------
__global__ __launch_bounds__(256) void k_proto_reduce(
    const float* __restrict__ Ppart, unsigned short* __restrict__ Pbf) {
  int idx = blockIdx.x * 256 + threadIdx.x;  // 0..NC*ED-1
  int kq = idx >> 9;
  int n = (idx >> 3) & 63;
  int j = idx & 7;
  int d = kq * 8 + j;
  float s = 0.f;
#pragma unroll 8
  for (int b = 0; b < PBLK; ++b) s += Ppart[(size_t)b * NC * ED + n * ED + d];
  Pbf[idx] = f2bf(s);
}

// ---------------------------------------------------------------------------
// K4: class_scores = (emb_q @ P^T) / ||q|| + fused softmax.
// ---------------------------------------------------------------------------
__global__ __launch_bounds__(64) void k_scores(
    const unsigned short* __restrict__ embQ, const float* __restrict__ ssqQ,
    const unsigned short* __restrict__ Pbf, float* __restrict__ out) {
  int lane = threadIdx.x;
  int quad = lane >> 4, ml = lane & 15;
  int qrow0 = blockIdx.x * 16;

  fx4 acc[4];
#pragma unroll
  for (int i = 0; i < 4; ++i) acc[i] = fx4{0.f, 0.f, 0.f, 0.f};

#pragma unroll 4
  for (int ki = 0; ki < 16; ++ki) {
    sx8 a = *(const sx8*)&embQ[(size_t)(qrow0 + ml) * ED + ki * 32 + quad * 8];
#pragma unroll
    for (int nt = 0; nt < 4; ++nt) {
      sx8 b = *(const sx8*)&Pbf[((ki * 4 + quad) * 64 + nt * 16 + ml) * 8];
      acc[nt] = __builtin_amdgcn_mfma_f32_16x16x32_bf16(a, b, acc[nt], 0, 0, 0);
    }
  }

#pragma unroll
  for (int r = 0; r < 4; ++r) {
    int qq = qrow0 + quad * 4 + r;
    float scale = 1.0f / fmaxf(sqrtf(ssqQ[qq]), 1e-12f);
    float s[4];
#pragma unroll
    for (int nt = 0; nt < 4; ++nt) s[nt] = acc[nt][r] * scale;
    float m = fmaxf(fmaxf(s[0], s[1]), fmaxf(s[2], s[3]));
#pragma unroll
    for (int off = 1; off < 16; off <<= 1) m = fmaxf(m, __shfl_xor(m, off, 16));
    float e[4], ssum = 0.f;
#pragma unroll
    for (int nt = 0; nt < 4; ++nt) { e[nt] = __expf(s[nt] - m); ssum += e[nt]; }
#pragma unroll
    for (int off = 1; off < 16; off <<= 1) ssum += __shfl_xor(ssum, off, 16);
    float inv = 1.0f / ssum;
#pragma unroll
    for (int nt = 0; nt < 4; ++nt)
      out[(size_t)qq * NC + nt * 16 + ml] = e[nt] * inv;
  }
}

// ---------------------------------------------------------------------------
extern "C" void kernel_launch(void* const* d_in, const int* in_sizes, int n_in,
                              void* d_out, int out_size, void* d_ws, size_t ws_size,
                              hipStream_t stream) {
  const float* Xs     = (const float*)d_in[0];  // support_data [8192,1024]
  const int*   labels = (const int*)d_in[1];    // support_labels [8192]
  const float* Xq     = (const float*)d_in[2];  // query_data [8192,1024]
  const float* W      = (const float*)d_in[3];  // W [1024,512]
  float* out = (float*)d_out;

  char* ws = (char*)d_ws;
  size_t off = 0;
  unsigned short* Wt  = (unsigned short*)(ws + off); off += (size_t)ED * KDIM * 2;    // 1 MB
  unsigned short* emb = (unsigned short*)(ws + off); off += (size_t)NTOT * ED * 2;    // 16 MB
  float* rowssq = (float*)(ws + off); off += (size_t)NTOT * 4;                        // 64 KB
  float* Ppart  = (float*)(ws + off); off += (size_t)PBLK * NC * ED * 4;              // 8 MB
  unsigned short* Pbf = (unsigned short*)(ws + off); off += (size_t)NC * ED * 2;      // 64 KB

  k_prep<<<512, 256, 0, stream>>>(W, Wt, rowssq);
  k_gemm_embed<<<512, 256, 0, stream>>>(Xs, Xq, Wt, emb, rowssq);
  k_proto_partial<<<dim3(PBLK, 8), 256, 0, stream>>>(emb, rowssq, labels, Ppart);
  k_proto_reduce<<<NC * ED / 256, 256, 0, stream>>>(Ppart, Pbf);
  k_scores<<<NQ / 16, 64, 0, stream>>>(emb + (size_t)NS * ED, rowssq + NS, Pbf, out);
}

// Round 6
// 177.316 us; speedup vs baseline: 1.4927x; 1.4927x over previous
//
#include <hip/hip_runtime.h>
#include <hip/hip_bf16.h>

#define NS 8192
#define NQ 8192
#define NTOT 16384
#define KDIM 1024
#define ED 512
#define NC 64
#define PBLK 64   // proto partial row-chunks along support dim

typedef __attribute__((ext_vector_type(4))) float fx4;
typedef __attribute__((ext_vector_type(4))) int ix4;
typedef __attribute__((ext_vector_type(8))) short sx8;
typedef __attribute__((ext_vector_type(4))) unsigned short ux4;
typedef __attribute__((ext_vector_type(8))) unsigned short ux8;

__device__ __forceinline__ unsigned short f2bf(float f) {
  union { float f; unsigned u; } v; v.f = f;
  unsigned r = v.u + 0x7fffu + ((v.u >> 16) & 1u);   // RNE
  return (unsigned short)(r >> 16);
}
__device__ __forceinline__ float bf2f(unsigned short h) {
  union { unsigned u; float f; } v; v.u = ((unsigned)h) << 16;
  return v.f;
}

// async global->LDS DMA, 16 B per lane. LDS dest = wave-uniform base + lane*16.
__device__ __forceinline__ void async_ld16(const void* g, void* l) {
  __builtin_amdgcn_global_load_lds(
      (const __attribute__((address_space(1))) unsigned int*)g,
      (__attribute__((address_space(3))) unsigned int*)l, 16, 0, 0);
}

// ---------------------------------------------------------------------------
// K0: W -> Wt bf16 (B^T), 512 blocks; also zeroes rowssq (32 floats/block).
// ---------------------------------------------------------------------------
__global__ __launch_bounds__(256) void k_prep(
    const float* __restrict__ W, unsigned short* __restrict__ Wt,
    float* __restrict__ rowssq) {
  __shared__ float tile[32][33];
  int bid = blockIdx.x;            // 0..511
  int t = threadIdx.x;
  int k0 = (bid & 31) * 32;
  int n0 = (bid >> 5) * 32;
  int tx = t & 31, ty = t >> 5;
#pragma unroll
  for (int i = ty; i < 32; i += 8)
    tile[i][tx] = W[(size_t)(k0 + i) * ED + n0 + tx];
  __syncthreads();
#pragma unroll
  for (int i = ty; i < 32; i += 8)
    Wt[(size_t)(n0 + i) * KDIM + k0 + tx] = f2bf(tile[tx][i]);
  if (t < 32) rowssq[bid * 32 + t] = 0.f;
}

// ---------------------------------------------------------------------------
// K1: emb = bf16(X) @ W + per-row ssq partials, X read as fp32, fused cvt.
// R4 POST-MORTEM FIX: R3's av[2][4][2] was runtime-indexed (slot = kt&1 in
// a rolled loop) -> scratch allocation (rule #20): VGPR=104, WRITE_SIZE
// 300 MB (scratch spill traffic), 137 us. Fix: unroll K-loop by 2 with
// NAMED buffers avA/avB so every index is compile-time. Slot rotation is
// identical to the intended schedule:
//   even kt: loadA(kt+2)->avA, MFMA on buf0, writeA(avB)->Ash[1]
//   odd  kt: loadA(kt+2)->avB, MFMA on buf1, writeA(avA)->Ash[0]
// Pipeline (T3/T4): raw s_barrier + counted vmcnt, depth-2 A prefetch.
//   per-step VMEM FIFO: [8 A(kt+1)] [4 B(kt+1)] [8 A(kt+2)]
//   writeA reg-deps auto-wait vmcnt<=12; explicit vmcnt(8) retires the
//   B-DMAs; 8 A(kt+2) reg-loads legally cross s_barrier.
// LDS layout/swizzle identical to verified round-1 (slot = kq^(m&7)).
// Verification signal: VGPR ~180-210 & WRITE_SIZE ~18.5 MB => fix landed.
// ---------------------------------------------------------------------------
__global__ __launch_bounds__(256) void k_gemm_embed(
    const float* __restrict__ Xs, const float* __restrict__ Xq,
    const unsigned short* __restrict__ Wt,
    unsigned short* __restrict__ emb, float* __restrict__ rowssq) {
  __shared__ unsigned short Ash[2][128 * 8 * 8];  // 16 KB per buf, [m*8+slot][8]
  __shared__ unsigned short Bsh[2][128 * 8 * 8];  // 16 KB per buf, [n*8+slot][8]

  int lid = blockIdx.x;            // 0..511
  int x = lid & 7;                 // xcd (dispatch round-robin heuristic)
  int s = lid >> 3;                // 0..63
  int m_blk = x * 16 + (s >> 2);   // 0..127
  int n_blk = s & 3;               // 0..3

  const float* Xsrc = (m_blk < 64)
      ? (Xs + (size_t)m_blk * 128 * KDIM)
      : (Xq + (size_t)(m_blk - 64) * 128 * KDIM);
  const unsigned short* Wrow = Wt + (size_t)n_blk * 128 * KDIM;

  int t = threadIdx.x;
  int lane = t & 63, w = t >> 6;
  int wm = w >> 1, wn = w & 1;
  int quad = lane >> 4, ml = lane & 15;

  fx4 acc[4][4];
#pragma unroll
  for (int i = 0; i < 4; ++i)
#pragma unroll
    for (int j = 0; j < 4; ++j) acc[i][j] = fx4{0.f, 0.f, 0.f, 0.f};

  fx4 avA[4][2], avB[4][2];   // NAMED double-buffer: always static-indexed

  auto loadA = [&](int kt, fx4 (&av)[4][2]) {
    int k0 = kt * 64;
#pragma unroll
    for (int c = 0; c < 4; ++c) {            // A: 1024 chunks of 8, 4/thread
      int ch = t + 256 * c;
      int m = ch >> 3, kq = ch & 7;          // kq = GLOBAL k-octet
      const float* g = &Xsrc[(size_t)m * KDIM + k0 + kq * 8];
      av[c][0] = *(const fx4*)g;
      av[c][1] = *(const fx4*)(g + 4);
    }
  };
  auto writeA = [&](const fx4 (&av)[4][2], int bbuf) {
#pragma unroll
    for (int c = 0; c < 4; ++c) {
      int ch = t + 256 * c;
      int m = ch >> 3, kq = ch & 7;
      ux8 o;
      o[0] = f2bf(av[c][0].x); o[1] = f2bf(av[c][0].y);
      o[2] = f2bf(av[c][0].z); o[3] = f2bf(av[c][0].w);
      o[4] = f2bf(av[c][1].x); o[5] = f2bf(av[c][1].y);
      o[6] = f2bf(av[c][1].z); o[7] = f2bf(av[c][1].w);
      // global kq lands in slot kq^(m&7): identical layout to DMA path
      *(ux8*)&Ash[bbuf][((m * 8) + (kq ^ (m & 7))) * 8] = o;
    }
  };
  auto stageB = [&](int kt, int b) {
    int k0 = kt * 64;
#pragma unroll
    for (int c = 0; c < 4; ++c) {            // B: 1024 chunks, 4/thread
      int ch = t + 256 * c;
      int n = ch >> 3;
      int kq = (ch & 7) ^ (n & 7);           // global-side swizzle
      async_ld16(&Wrow[(size_t)n * KDIM + k0 + kq * 8],
                 &Bsh[b][(w * 64 + 256 * c) * 8]);
    }
  };
  auto compute = [&](int b) {
#pragma unroll
    for (int s2 = 0; s2 < 2; ++s2) {
      int kq = s2 * 4 + quad;
      sx8 af[4], bfr[4];
#pragma unroll
      for (int i = 0; i < 4; ++i) {
        int row = wm * 64 + i * 16 + ml;
        af[i] = *(const sx8*)&Ash[b][(row * 8 + (kq ^ (row & 7))) * 8];
      }
#pragma unroll
      for (int j = 0; j < 4; ++j) {
        int nrow = wn * 64 + j * 16 + ml;
        bfr[j] = *(const sx8*)&Bsh[b][(nrow * 8 + (kq ^ (nrow & 7))) * 8];
      }
#pragma unroll
      for (int i = 0; i < 4; ++i)
#pragma unroll
        for (int j = 0; j < 4; ++j)
          acc[i][j] = __builtin_amdgcn_mfma_f32_16x16x32_bf16(af[i], bfr[j], acc[i][j], 0, 0, 0);
    }
  };

  // ---- prologue: FIFO = [4 B(0)] [8 A(0)->avA] [8 A(1)->avB]
  stageB(0, 0);
  __builtin_amdgcn_sched_barrier(0);
  loadA(0, avA);
  loadA(1, avB);
  __builtin_amdgcn_sched_barrier(0);
  writeA(avA, 0);      // auto-wait retires B(0)+A(0); A(1)->avB in flight
  asm volatile("s_waitcnt vmcnt(8) lgkmcnt(0)" ::: "memory");
  __builtin_amdgcn_sched_barrier(0);
  __builtin_amdgcn_s_barrier();

  for (int it = 0; it < 8; ++it) {
    int kt0 = it * 2;
    // ---- even step: kt = kt0, buf 0. avB holds A(kt0+1) (in flight).
    stageB(kt0 + 1, 1);                          // 4 DMAs -> Bsh[1]
    __builtin_amdgcn_sched_barrier(0);           // pin FIFO: B before A
    loadA(kt0 + 2 < 16 ? kt0 + 2 : 15, avA);     // 8 loads -> avA

    __builtin_amdgcn_s_setprio(1);
    compute(0);
    __builtin_amdgcn_s_setprio(0);

    writeA(avB, 1);    // cvt A(kt0+1) (auto vmcnt wait) -> Ash[1]
    // retire the 4 B DMAs + commit ds_writes; keep 8 avA loads in flight
    asm volatile("s_waitcnt vmcnt(8) lgkmcnt(0)" ::: "memory");
    __builtin_amdgcn_sched_barrier(0);
    __builtin_amdgcn_s_barrier();

    // ---- odd step: kt = kt0+1, buf 1. avA holds A(kt0+2) (in flight).
    stageB(kt0 + 2 < 16 ? kt0 + 2 : 15, 0);      // 4 DMAs -> Bsh[0]
    __builtin_amdgcn_sched_barrier(0);
    loadA(kt0 + 3 < 16 ? kt0 + 3 : 15, avB);     // 8 loads -> avB

    __builtin_amdgcn_s_setprio(1);
    compute(1);
    __builtin_amdgcn_s_setprio(0);

    writeA(avA, 0);    // cvt A(kt0+2) -> Ash[0]
    asm volatile("s_waitcnt vmcnt(8) lgkmcnt(0)" ::: "memory");
    __builtin_amdgcn_sched_barrier(0);
    __builtin_amdgcn_s_barrier();
  }

  // epilogue: emb store + row-ssq partial (shfl width-16 + 1 atomic per row)
  int grow = m_blk * 128 + wm * 64;
  int gcol = n_blk * 128 + wn * 64;
#pragma unroll
  for (int i = 0; i < 4; ++i) {
#pragma unroll
    for (int r = 0; r < 4; ++r) {
      int mrow = grow + i * 16 + quad * 4 + r;
      float p = 0.f;
#pragma unroll
      for (int j = 0; j < 4; ++j) {
        emb[(size_t)mrow * ED + gcol + j * 16 + ml] = f2bf(acc[i][j][r]);
        p += acc[i][j][r] * acc[i][j][r];
      }
#pragma unroll
      for (int off = 1; off < 16; off <<= 1) p += __shfl_xor(p, off, 16);
      if (ml == 0) atomicAdd(&rowssq[mrow], p);
    }
  }
}

// ---------------------------------------------------------------------------
// K2: per-class partial sums of (emb_s / ||s||), LDS-accumulated.
// ---------------------------------------------------------------------------
__global__ __launch_bounds__(256) void k_proto_partial(
    const unsigned short* __restrict__ embS, const float* __restrict__ rowssq,
    const int* __restrict__ labels, float* __restrict__ Ppart) {
  __shared__ float Pl[NC * 64];  // 16 KB: [class][dim-within-slice]
  int t = threadIdx.x;
#pragma unroll
  for (int i = 0; i < 16; ++i) Pl[i * 256 + t] = 0.f;
  __syncthreads();

  int w = t >> 6, lane = t & 63;
  int ds = blockIdx.y;            // dim slice: dims [ds*64, ds*64+64)
  int row0 = blockIdx.x * (NS / PBLK);
#pragma unroll 4
  for (int r = w; r < NS / PBLK; r += 4) {
    int row = row0 + r;
    int lbl = labels[row];
    float scale = 1.0f / fmaxf(sqrtf(rowssq[row]), 1e-12f);
    float v = bf2f(embS[(size_t)row * ED + ds * 64 + lane]) * scale;
    atomicAdd(&Pl[lbl * 64 + lane], v);
  }
  __syncthreads();

  float* o = Ppart + (size_t)blockIdx.x * NC * ED + ds * 64;
#pragma unroll
  for (int i = 0; i < 16; ++i) {
    int idx = i * 256 + t;
    o[(size_t)(idx >> 6) * ED + (idx & 63)] = Pl[idx];
  }
}

// ---------------------------------------------------------------------------
// K3: reduce PBLK partials -> Pbf (bf16, MFMA B-fragment layout [kq][n][8]).
// ---------------------------------------------------------------------------
__global__ __launch_bounds__(256) void k_proto_reduce(
    const float* __restrict__ Ppart, unsigned short* __restrict__ Pbf) {
  int idx = blockIdx.x * 256 + threadIdx.x;  // 0..NC*ED-1
  int kq = idx >> 9;
  int n = (idx >> 3) & 63;
  int j = idx & 7;
  int d = kq * 8 + j;
  float s = 0.f;
#pragma unroll 8
  for (int b = 0; b < PBLK; ++b) s += Ppart[(size_t)b * NC * ED + n * ED + d];
  Pbf[idx] = f2bf(s);
}

// ---------------------------------------------------------------------------
// K4: class_scores = (emb_q @ P^T) / ||q|| + fused softmax.
// ---------------------------------------------------------------------------
__global__ __launch_bounds__(64) void k_scores(
    const unsigned short* __restrict__ embQ, const float* __restrict__ ssqQ,
    const unsigned short* __restrict__ Pbf, float* __restrict__ out) {
  int lane = threadIdx.x;
  int quad = lane >> 4, ml = lane & 15;
  int qrow0 = blockIdx.x * 16;

  fx4 acc[4];
#pragma unroll
  for (int i = 0; i < 4; ++i) acc[i] = fx4{0.f, 0.f, 0.f, 0.f};

#pragma unroll 4
  for (int ki = 0; ki < 16; ++ki) {
    sx8 a = *(const sx8*)&embQ[(size_t)(qrow0 + ml) * ED + ki * 32 + quad * 8];
#pragma unroll
    for (int nt = 0; nt < 4; ++nt) {
      sx8 b = *(const sx8*)&Pbf[((ki * 4 + quad) * 64 + nt * 16 + ml) * 8];
      acc[nt] = __builtin_amdgcn_mfma_f32_16x16x32_bf16(a, b, acc[nt], 0, 0, 0);
    }
  }

#pragma unroll
  for (int r = 0; r < 4; ++r) {
    int qq = qrow0 + quad * 4 + r;
    float scale = 1.0f / fmaxf(sqrtf(ssqQ[qq]), 1e-12f);
    float s[4];
#pragma unroll
    for (int nt = 0; nt < 4; ++nt) s[nt] = acc[nt][r] * scale;
    float m = fmaxf(fmaxf(s[0], s[1]), fmaxf(s[2], s[3]));
#pragma unroll
    for (int off = 1; off < 16; off <<= 1) m = fmaxf(m, __shfl_xor(m, off, 16));
    float e[4], ssum = 0.f;
#pragma unroll
    for (int nt = 0; nt < 4; ++nt) { e[nt] = __expf(s[nt] - m); ssum += e[nt]; }
#pragma unroll
    for (int off = 1; off < 16; off <<= 1) ssum += __shfl_xor(ssum, off, 16);
    float inv = 1.0f / ssum;
#pragma unroll
    for (int nt = 0; nt < 4; ++nt)
      out[(size_t)qq * NC + nt * 16 + ml] = e[nt] * inv;
  }
}

// ---------------------------------------------------------------------------
extern "C" void kernel_launch(void* const* d_in, const int* in_sizes, int n_in,
                              void* d_out, int out_size, void* d_ws, size_t ws_size,
                              hipStream_t stream) {
  const float* Xs     = (const float*)d_in[0];  // support_data [8192,1024]
  const int*   labels = (const int*)d_in[1];    // support_labels [8192]
  const float* Xq     = (const float*)d_in[2];  // query_data [8192,1024]
  const float* W      = (const float*)d_in[3];  // W [1024,512]
  float* out = (float*)d_out;

  char* ws = (char*)d_ws;
  size_t off = 0;
  unsigned short* Wt  = (unsigned short*)(ws + off); off += (size_t)ED * KDIM * 2;    // 1 MB
  unsigned short* emb = (unsigned short*)(ws + off); off += (size_t)NTOT * ED * 2;    // 16 MB
  float* rowssq = (float*)(ws + off); off += (size_t)NTOT * 4;                        // 64 KB
  float* Ppart  = (float*)(ws + off); off += (size_t)PBLK * NC * ED * 4;              // 8 MB
  unsigned short* Pbf = (unsigned short*)(ws + off); off += (size_t)NC * ED * 2;      // 64 KB

  k_prep<<<512, 256, 0, stream>>>(W, Wt, rowssq);
  k_gemm_embed<<<512, 256, 0, stream>>>(Xs, Xq, Wt, emb, rowssq);
  k_proto_partial<<<dim3(PBLK, 8), 256, 0, stream>>>(emb, rowssq, labels, Ppart);
  k_proto_reduce<<<NC * ED / 256, 256, 0, stream>>>(Ppart, Pbf);
  k_scores<<<NQ / 16, 64, 0, stream>>>(emb + (size_t)NS * ED, rowssq + NS, Pbf, out);
}

// Round 7
// 172.704 us; speedup vs baseline: 1.5326x; 1.0267x over previous
//
#include <hip/hip_runtime.h>
#include <hip/hip_bf16.h>

#define NS 8192
#define NQ 8192
#define NTOT 16384
#define KDIM 1024
#define ED 512
#define NC 64
#define PBLK 64   // proto partial row-chunks along support dim

typedef __attribute__((ext_vector_type(4))) float fx4;
typedef __attribute__((ext_vector_type(8))) short sx8;
typedef __attribute__((ext_vector_type(8))) unsigned short ux8;

__device__ __forceinline__ unsigned short f2bf(float f) {
  union { float f; unsigned u; } v; v.f = f;
  unsigned r = v.u + 0x7fffu + ((v.u >> 16) & 1u);   // RNE
  return (unsigned short)(r >> 16);
}
__device__ __forceinline__ float bf2f(unsigned short h) {
  union { unsigned u; float f; } v; v.u = ((unsigned)h) << 16;
  return v.f;
}

// ---------------------------------------------------------------------------
// K0: W -> Wtp, bf16 in MFMA B-FRAGMENT-PACKED order:
//   flat chunk c = n64*8192 + kt*512 + s2*256 + j*64 + lane   (c in [0,65536))
//   chunk c holds B[n][kb..kb+8) where n = n64*64 + j*16 + (lane&15),
//   kb = kt*64 + (s2*4 + (lane>>4))*8.
// In k_gemm a wave loads bf[s2][j] as ONE coalesced 1KB global_load_dwordx4
// (lane-consecutive chunks) -> B never touches LDS. Also zeroes rowssq.
// ---------------------------------------------------------------------------
__global__ __launch_bounds__(256) void k_prep(
    const float* __restrict__ W, unsigned short* __restrict__ Wtp,
    float* __restrict__ rowssq) {
  int c = blockIdx.x * 256 + threadIdx.x;   // 0..65535
  int lane = c & 63;
  int j    = (c >> 6) & 3;
  int s2   = (c >> 8) & 1;
  int kt   = (c >> 9) & 15;
  int n64  = c >> 13;
  int quad = lane >> 4, ml = lane & 15;
  int n  = n64 * 64 + j * 16 + ml;
  int kb = kt * 64 + (s2 * 4 + quad) * 8;
  ux8 o;
#pragma unroll
  for (int e = 0; e < 8; ++e) o[e] = f2bf(W[(size_t)(kb + e) * ED + n]);
  *(ux8*)&Wtp[(size_t)c * 8] = o;
  if (c < NTOT) rowssq[c] = 0.f;
}

// ---------------------------------------------------------------------------
// K1: emb = bf16(X) @ W + per-row ssq, X read as fp32 with fused cvt.
// R6 POST-MORTEM: traffic was ideal (FETCH 37MB, WRITE 18.4MB) but MfmaUtil
// stuck at 12% — the step was fat: 96KB LDS traffic/block/step (A+B staging)
// + a vmcnt+lgkm+barrier bundle each step at 2 waves/SIMD. Fix: B bypasses
// LDS entirely via fragment-packed Wtp (see k_prep): per step each wave does
// 8 coalesced 1KB loads straight into B-fragment registers (L2-hot, 1MB).
//   - LDS traffic halved: only A (write 16KB + read 32KB per block/step)
//   - NO vmcnt wait in the loop: the only outstanding VMEM are reg-targeted
//     loads (A depth-2 prefetch + B), ordered by compiler auto-waits; the
//     barrier needs only lgkmcnt(0) (commit A ds_writes).
//   - LDS 32KB/block (was 64KB).
// A path identical to R6: named avA/avB (rule #20), unroll-by-2 rotation,
// swizzled ds_write slot = kq^(m&7); MFMA order bit-identical to R6.
// Spill check next profile: WRITE_SIZE must stay ~18.4MB.
// ---------------------------------------------------------------------------
__global__ __launch_bounds__(256) void k_gemm_embed(
    const float* __restrict__ Xs, const float* __restrict__ Xq,
    const unsigned short* __restrict__ Wtp,
    unsigned short* __restrict__ emb, float* __restrict__ rowssq) {
  __shared__ unsigned short Ash[2][128 * 8 * 8];  // 16 KB per buf, [m*8+slot][8]

  int lid = blockIdx.x;            // 0..511
  int x = lid & 7;                 // xcd round-robin heuristic
  int s = lid >> 3;                // 0..63
  int m_blk = x * 16 + (s >> 2);   // 0..127
  int n_blk = s & 3;               // 0..3

  const float* Xsrc = (m_blk < 64)
      ? (Xs + (size_t)m_blk * 128 * KDIM)
      : (Xq + (size_t)(m_blk - 64) * 128 * KDIM);

  int t = threadIdx.x;
  int lane = t & 63, w = t >> 6;
  int wm = w >> 1, wn = w & 1;
  int quad = lane >> 4, ml = lane & 15;
  int n64 = n_blk * 2 + wn;        // 0..7: this wave's 64-col B slice

  // per-wave B fragment base: chunk (n64*8192 + lane), element *8
  const unsigned short* Bbase = Wtp + ((size_t)n64 * 8192 + lane) * 8;

  fx4 acc[4][4];
#pragma unroll
  for (int i = 0; i < 4; ++i)
#pragma unroll
    for (int j = 0; j < 4; ++j) acc[i][j] = fx4{0.f, 0.f, 0.f, 0.f};

  fx4 avA[4][2], avB[4][2];   // NAMED A double-buffer (rule #20)

  auto loadA = [&](int kt, fx4 (&av)[4][2]) {
    int k0 = kt * 64;
#pragma unroll
    for (int c = 0; c < 4; ++c) {            // A: 1024 chunks of 8, 4/thread
      int ch = t + 256 * c;
      int m = ch >> 3, kq = ch & 7;          // kq = GLOBAL k-octet
      const float* g = &Xsrc[(size_t)m * KDIM + k0 + kq * 8];
      av[c][0] = *(const fx4*)g;
      av[c][1] = *(const fx4*)(g + 4);
    }
  };
  auto writeA = [&](const fx4 (&av)[4][2], int bbuf) {
#pragma unroll
    for (int c = 0; c < 4; ++c) {
      int ch = t + 256 * c;
      int m = ch >> 3, kq = ch & 7;
      ux8 o;
      o[0] = f2bf(av[c][0].x); o[1] = f2bf(av[c][0].y);
      o[2] = f2bf(av[c][0].z); o[3] = f2bf(av[c][0].w);
      o[4] = f2bf(av[c][1].x); o[5] = f2bf(av[c][1].y);
      o[6] = f2bf(av[c][1].z); o[7] = f2bf(av[c][1].w);
      *(ux8*)&Ash[bbuf][((m * 8) + (kq ^ (m & 7))) * 8] = o;   // slot swizzle
    }
  };
  auto loadB = [&](int kt, sx8 (&bf)[2][4]) {
#pragma unroll
    for (int s2 = 0; s2 < 2; ++s2)
#pragma unroll
      for (int j = 0; j < 4; ++j)
        bf[s2][j] = *(const sx8*)&Bbase[(size_t)(kt * 512 + s2 * 256 + j * 64) * 8];
  };
  auto compute = [&](int b, const sx8 (&bf)[2][4]) {
#pragma unroll
    for (int s2 = 0; s2 < 2; ++s2) {
      int kq = s2 * 4 + quad;
      sx8 af[4];
#pragma unroll
      for (int i = 0; i < 4; ++i) {
        int row = wm * 64 + i * 16 + ml;
        af[i] = *(const sx8*)&Ash[b][(row * 8 + (kq ^ (row & 7))) * 8];
      }
#pragma unroll
      for (int i = 0; i < 4; ++i)
#pragma unroll
        for (int j = 0; j < 4; ++j)
          acc[i][j] = __builtin_amdgcn_mfma_f32_16x16x32_bf16(af[i], bf[s2][j], acc[i][j], 0, 0, 0);
    }
  };
  auto sync_step = [&]() {
    // only LDS ordering needed: A ds_writes commit; reg-loads stay in flight
    __builtin_amdgcn_sched_barrier(0);
    asm volatile("s_waitcnt lgkmcnt(0)" ::: "memory");
    __builtin_amdgcn_s_barrier();
    __builtin_amdgcn_sched_barrier(0);
  };

  // ---- prologue: A(0)->avA->Ash[0]; A(1)->avB stays in flight
  loadA(0, avA);
  loadA(1, avB);
  writeA(avA, 0);        // auto vmcnt wait on avA only
  sync_step();

  for (int it = 0; it < 8; ++it) {
    int kt0 = it * 2;
    sx8 bf[2][4];
    // ---- even step kt0, compute from Ash[0]; avB holds A(kt0+1) in flight
    loadB(kt0, bf);
    loadA(kt0 + 2 < 16 ? kt0 + 2 : 15, avA);
    compute(0, bf);
    writeA(avB, 1);      // cvt A(kt0+1) (auto-wait, ~1 step of cover) -> Ash[1]
    sync_step();

    // ---- odd step kt0+1, compute from Ash[1]; avA holds A(kt0+2) in flight
    loadB(kt0 + 1, bf);
    loadA(kt0 + 3 < 16 ? kt0 + 3 : 15, avB);
    compute(1, bf);
    writeA(avA, 0);      // cvt A(kt0+2) -> Ash[0]
    sync_step();
  }

  // epilogue: emb store + row-ssq partial (shfl width-16 + 1 atomic per row)
  int grow = m_blk * 128 + wm * 64;
  int gcol = n_blk * 128 + wn * 64;
#pragma unroll
  for (int i = 0; i < 4; ++i) {
#pragma unroll
    for (int r = 0; r < 4; ++r) {
      int mrow = grow + i * 16 + quad * 4 + r;
      float p = 0.f;
#pragma unroll
      for (int j = 0; j < 4; ++j) {
        emb[(size_t)mrow * ED + gcol + j * 16 + ml] = f2bf(acc[i][j][r]);
        p += acc[i][j][r] * acc[i][j][r];
      }
#pragma unroll
      for (int off = 1; off < 16; off <<= 1) p += __shfl_xor(p, off, 16);
      if (ml == 0) atomicAdd(&rowssq[mrow], p);
    }
  }
}

// ---------------------------------------------------------------------------
// K2: per-class partial sums of (emb_s / ||s||), LDS-accumulated.
// ---------------------------------------------------------------------------
__global__ __launch_bounds__(256) void k_proto_partial(
    const unsigned short* __restrict__ embS, const float* __restrict__ rowssq,
    const int* __restrict__ labels, float* __restrict__ Ppart) {
  __shared__ float Pl[NC * 64];  // 16 KB: [class][dim-within-slice]
  int t = threadIdx.x;
#pragma unroll
  for (int i = 0; i < 16; ++i) Pl[i * 256 + t] = 0.f;
  __syncthreads();

  int w = t >> 6, lane = t & 63;
  int ds = blockIdx.y;            // dim slice: dims [ds*64, ds*64+64)
  int row0 = blockIdx.x * (NS / PBLK);
#pragma unroll 4
  for (int r = w; r < NS / PBLK; r += 4) {
    int row = row0 + r;
    int lbl = labels[row];
    float scale = 1.0f / fmaxf(sqrtf(rowssq[row]), 1e-12f);
    float v = bf2f(embS[(size_t)row * ED + ds * 64 + lane]) * scale;
    atomicAdd(&Pl[lbl * 64 + lane], v);
  }
  __syncthreads();

  float* o = Ppart + (size_t)blockIdx.x * NC * ED + ds * 64;
#pragma unroll
  for (int i = 0; i < 16; ++i) {
    int idx = i * 256 + t;
    o[(size_t)(idx >> 6) * ED + (idx & 63)] = Pl[idx];
  }
}

// ---------------------------------------------------------------------------
// K3: reduce PBLK partials -> Pbf (bf16, MFMA B-fragment layout [kq][n][8]).
// ---------------------------------------------------------------------------
__global__ __launch_bounds__(256) void k_proto_reduce(
    const float* __restrict__ Ppart, unsigned short* __restrict__ Pbf) {
  int idx = blockIdx.x * 256 + threadIdx.x;  // 0..NC*ED-1
  int kq = idx >> 9;
  int n = (idx >> 3) & 63;
  int j = idx & 7;
  int d = kq * 8 + j;
  float s = 0.f;
#pragma unroll 8
  for (int b = 0; b < PBLK; ++b) s += Ppart[(size_t)b * NC * ED + n * ED + d];
  Pbf[idx] = f2bf(s);
}

// ---------------------------------------------------------------------------
// K4: class_scores = (emb_q @ P^T) / ||q|| + fused softmax.
// ---------------------------------------------------------------------------
__global__ __launch_bounds__(64) void k_scores(
    const unsigned short* __restrict__ embQ, const float* __restrict__ ssqQ,
    const unsigned short* __restrict__ Pbf, float* __restrict__ out) {
  int lane = threadIdx.x;
  int quad = lane >> 4, ml = lane & 15;
  int qrow0 = blockIdx.x * 16;

  fx4 acc[4];
#pragma unroll
  for (int i = 0; i < 4; ++i) acc[i] = fx4{0.f, 0.f, 0.f, 0.f};

#pragma unroll 4
  for (int ki = 0; ki < 16; ++ki) {
    sx8 a = *(const sx8*)&embQ[(size_t)(qrow0 + ml) * ED + ki * 32 + quad * 8];
#pragma unroll
    for (int nt = 0; nt < 4; ++nt) {
      sx8 b = *(const sx8*)&Pbf[((ki * 4 + quad) * 64 + nt * 16 + ml) * 8];
      acc[nt] = __builtin_amdgcn_mfma_f32_16x16x32_bf16(a, b, acc[nt], 0, 0, 0);
    }
  }

#pragma unroll
  for (int r = 0; r < 4; ++r) {
    int qq = qrow0 + quad * 4 + r;
    float scale = 1.0f / fmaxf(sqrtf(ssqQ[qq]), 1e-12f);
    float s[4];
#pragma unroll
    for (int nt = 0; nt < 4; ++nt) s[nt] = acc[nt][r] * scale;
    float m = fmaxf(fmaxf(s[0], s[1]), fmaxf(s[2], s[3]));
#pragma unroll
    for (int off = 1; off < 16; off <<= 1) m = fmaxf(m, __shfl_xor(m, off, 16));
    float e[4], ssum = 0.f;
#pragma unroll
    for (int nt = 0; nt < 4; ++nt) { e[nt] = __expf(s[nt] - m); ssum += e[nt]; }
#pragma unroll
    for (int off = 1; off < 16; off <<= 1) ssum += __shfl_xor(ssum, off, 16);
    float inv = 1.0f / ssum;
#pragma unroll
    for (int nt = 0; nt < 4; ++nt)
      out[(size_t)qq * NC + nt * 16 + ml] = e[nt] * inv;
  }
}

// ---------------------------------------------------------------------------
extern "C" void kernel_launch(void* const* d_in, const int* in_sizes, int n_in,
                              void* d_out, int out_size, void* d_ws, size_t ws_size,
                              hipStream_t stream) {
  const float* Xs     = (const float*)d_in[0];  // support_data [8192,1024]
  const int*   labels = (const int*)d_in[1];    // support_labels [8192]
  const float* Xq     = (const float*)d_in[2];  // query_data [8192,1024]
  const float* W      = (const float*)d_in[3];  // W [1024,512]
  float* out = (float*)d_out;

  char* ws = (char*)d_ws;
  size_t off = 0;
  unsigned short* Wtp = (unsigned short*)(ws + off); off += (size_t)ED * KDIM * 2;    // 1 MB (fragment-packed)
  unsigned short* emb = (unsigned short*)(ws + off); off += (size_t)NTOT * ED * 2;    // 16 MB
  float* rowssq = (float*)(ws + off); off += (size_t)NTOT * 4;                        // 64 KB
  float* Ppart  = (float*)(ws + off); off += (size_t)PBLK * NC * ED * 4;              // 8 MB
  unsigned short* Pbf = (unsigned short*)(ws + off); off += (size_t)NC * ED * 2;      // 64 KB

  k_prep<<<256, 256, 0, stream>>>(W, Wtp, rowssq);
  k_gemm_embed<<<512, 256, 0, stream>>>(Xs, Xq, Wtp, emb, rowssq);
  k_proto_partial<<<dim3(PBLK, 8), 256, 0, stream>>>(emb, rowssq, labels, Ppart);
  k_proto_reduce<<<NC * ED / 256, 256, 0, stream>>>(Ppart, Pbf);
  k_scores<<<NQ / 16, 64, 0, stream>>>(emb + (size_t)NS * ED, rowssq + NS, Pbf, out);
}